// Round 1
// baseline (1483.467 us; speedup 1.0000x reference)
//
#include <hip/hip_runtime.h>
#include <cstdint>
#include <cstddef>

#define NNODES 100000
#define NEDGES 3200000
#define NTOT   3300000   // edges + self loops
#define FIN    256
#define HH     64        // heads*hid (layer 1 out)
#define NH     8
#define C2     40
#define NEG    0.2f

// ---------------- CSR build ----------------

__global__ __launch_bounds__(256) void k_hist(const int* __restrict__ ei, int* __restrict__ deg) {
    int i = blockIdx.x * 256 + threadIdx.x;
    if (i >= NTOT) return;
    int d = (i < NEDGES) ? ei[NEDGES + i] : (i - NEDGES);
    atomicAdd(&deg[d], 1);
}

__global__ __launch_bounds__(1024) void k_scan(const int* __restrict__ deg, int* __restrict__ rowptr,
                                               int* __restrict__ wofs) {
    __shared__ int part[1024];
    const int CH = 98;  // 1024*98 >= 100000
    int t = threadIdx.x;
    int s0 = t * CH, s1 = s0 + CH;
    if (s1 > NNODES) s1 = NNODES;
    if (s0 > NNODES) s0 = NNODES;
    int s = 0;
    for (int i = s0; i < s1; ++i) s += deg[i];
    part[t] = s;
    __syncthreads();
    for (int off = 1; off < 1024; off <<= 1) {
        int v = (t >= off) ? part[t - off] : 0;
        __syncthreads();
        part[t] += v;
        __syncthreads();
    }
    int run = (t == 0) ? 0 : part[t - 1];
    for (int i = s0; i < s1; ++i) {
        rowptr[i] = run;
        wofs[i] = run;
        run += deg[i];
    }
    if (t == 1023) rowptr[NNODES] = run;
}

__global__ __launch_bounds__(256) void k_scatter(const int* __restrict__ ei, int* __restrict__ wofs,
                                                 int* __restrict__ esrc) {
    int i = blockIdx.x * 256 + threadIdx.x;
    if (i >= NTOT) return;
    int s, d;
    if (i < NEDGES) { s = ei[i]; d = ei[NEDGES + i]; }
    else            { s = d = i - NEDGES; }
    int p = atomicAdd(&wofs[d], 1);
    esrc[p] = s;
}

// ---------------- Layer 1 ----------------

// h1[N,64] = x[N,256] @ W1[256,64]
__global__ __launch_bounds__(256) void k_gemm1(const float* __restrict__ x, const float* __restrict__ W,
                                               float* __restrict__ h1) {
    __shared__ float xs[32][256];
    int t = threadIdx.x;
    size_t n0 = (size_t)blockIdx.x * 32;
    const float4* xg = (const float4*)(x + n0 * FIN);
    float4* xl = (float4*)(&xs[0][0]);
#pragma unroll
    for (int i = 0; i < 8; ++i) xl[t + i * 256] = xg[t + i * 256];
    __syncthreads();
    int c = t & 63, rg = t >> 6;
    float acc[8] = {0.f, 0.f, 0.f, 0.f, 0.f, 0.f, 0.f, 0.f};
    for (int k = 0; k < 256; k += 4) {
        float w0 = W[(k    ) * HH + c];
        float w1 = W[(k + 1) * HH + c];
        float w2 = W[(k + 2) * HH + c];
        float w3 = W[(k + 3) * HH + c];
#pragma unroll
        for (int i = 0; i < 8; ++i) {
            float4 xv = *(const float4*)&xs[rg * 8 + i][k];
            acc[i] = fmaf(xv.x, w0, acc[i]);
            acc[i] = fmaf(xv.y, w1, acc[i]);
            acc[i] = fmaf(xv.z, w2, acc[i]);
            acc[i] = fmaf(xv.w, w3, acc[i]);
        }
    }
#pragma unroll
    for (int i = 0; i < 8; ++i) h1[(n0 + rg * 8 + i) * HH + c] = acc[i];
}

// a_src1/a_dst1 [N,8]
__global__ __launch_bounds__(256) void k_att1(const float* __restrict__ h1, const float* __restrict__ asw,
                                              const float* __restrict__ adw, float* __restrict__ as,
                                              float* __restrict__ ad) {
    int i = blockIdx.x * 256 + threadIdx.x;  // < N*8, exact
    int h = i & 7;
    const float4* hp = (const float4*)(h1 + (size_t)i * 8);
    float4 a = hp[0], b = hp[1];
    const float4* sp = (const float4*)(asw + h * 8);
    const float4* dp = (const float4*)(adw + h * 8);
    float4 s0 = sp[0], s1 = sp[1], d0 = dp[0], d1 = dp[1];
    float sv = a.x * s0.x + a.y * s0.y + a.z * s0.z + a.w * s0.w +
               b.x * s1.x + b.y * s1.y + b.z * s1.z + b.w * s1.w;
    float dv = a.x * d0.x + a.y * d0.y + a.z * d0.z + a.w * d0.w +
               b.x * d1.x + b.y * d1.y + b.z * d1.z + b.w * d1.w;
    as[i] = sv;
    ad[i] = dv;
}

// one wave per node; lane t owns channel t (h = t>>3)
__global__ __launch_bounds__(256) void k_aggr1(const float* __restrict__ h1, const float* __restrict__ as,
                                               const float* __restrict__ ad, const int* __restrict__ rowptr,
                                               const int* __restrict__ esrc, const float* __restrict__ b1,
                                               float* __restrict__ hmid) {
    int wv = threadIdx.x >> 6, t = threadIdx.x & 63;
    int n = blockIdx.x * 4 + wv;
    int h = t >> 3;
    float adn = ad[n * NH + h];
    int beg = rowptr[n], end = rowptr[n + 1];
    float acc = 0.f, den = 0.f;
    for (int j = beg; j < end; ++j) {
        int s = esrc[j];
        float e = as[s * NH + h] + adn;
        e = (e > 0.f) ? e : NEG * e;
        float w = __expf(e);
        den += w;
        acc = fmaf(w, h1[(size_t)s * HH + t], acc);
    }
    float o = acc / (den + 1e-16f) + b1[t];
    hmid[(size_t)n * HH + t] = (o > 0.f) ? o : expm1f(o);  // ELU
}

// ---------------- Layer 2 ----------------

// h2[N,40] = hmid[N,64] @ W2[64,40]; also a_src2/a_dst2 [N]
__global__ __launch_bounds__(256) void k_gemm2(const float* __restrict__ hmid, const float* __restrict__ W2,
                                               const float* __restrict__ as2w, const float* __restrict__ ad2w,
                                               float* __restrict__ h2, float* __restrict__ as2,
                                               float* __restrict__ ad2) {
    __shared__ float w2s[64 * C2];
    __shared__ float hrow[4][64];
    int t = threadIdx.x;
    for (int i = t; i < 64 * C2; i += 256) w2s[i] = W2[i];
    __syncthreads();
    int wv = t >> 6, ln = t & 63;
    int n = blockIdx.x * 4 + wv;
    hrow[wv][ln] = hmid[(size_t)n * HH + ln];
    __syncthreads();
    float acc = 0.f;
    if (ln < C2) {
#pragma unroll 8
        for (int k = 0; k < 64; ++k) acc = fmaf(hrow[wv][k], w2s[k * C2 + ln], acc);
    }
    float sv = 0.f, dv = 0.f;
    if (ln < C2) {
        h2[(size_t)n * C2 + ln] = acc;
        sv = acc * as2w[ln];
        dv = acc * ad2w[ln];
    }
#pragma unroll
    for (int off = 32; off > 0; off >>= 1) {
        sv += __shfl_xor(sv, off);
        dv += __shfl_xor(dv, off);
    }
    if (ln == 0) { as2[n] = sv; ad2[n] = dv; }
}

// one wave per node; lane t<40 owns class t; fused log_softmax
__global__ __launch_bounds__(256) void k_aggr2(const float* __restrict__ h2, const float* __restrict__ as2,
                                               const float* __restrict__ ad2, const int* __restrict__ rowptr,
                                               const int* __restrict__ esrc, const float* __restrict__ b2,
                                               float* __restrict__ out) {
    int wv = threadIdx.x >> 6, t = threadIdx.x & 63;
    int n = blockIdx.x * 4 + wv;
    float adn = ad2[n];
    int beg = rowptr[n], end = rowptr[n + 1];
    float acc = 0.f, den = 0.f;
    bool act = (t < C2);
    for (int j = beg; j < end; ++j) {
        int s = esrc[j];
        float e = as2[s] + adn;
        e = (e > 0.f) ? e : NEG * e;
        float w = __expf(e);
        den += w;
        if (act) acc = fmaf(w, h2[(size_t)s * C2 + t], acc);
    }
    float o = act ? (acc / (den + 1e-16f) + b2[t]) : -1e30f;
    float m = o;
#pragma unroll
    for (int off = 32; off > 0; off >>= 1) m = fmaxf(m, __shfl_xor(m, off));
    float ex = act ? __expf(o - m) : 0.f;
    float sm = ex;
#pragma unroll
    for (int off = 32; off > 0; off >>= 1) sm += __shfl_xor(sm, off);
    if (act) out[(size_t)n * C2 + t] = o - m - logf(sm);
}

// ---------------- launch ----------------

extern "C" void kernel_launch(void* const* d_in, const int* in_sizes, int n_in,
                              void* d_out, int out_size, void* d_ws, size_t ws_size,
                              hipStream_t stream) {
    const float* x    = (const float*)d_in[0];
    const int*   ei   = (const int*)d_in[1];
    const float* W1   = (const float*)d_in[2];
    const float* as1w = (const float*)d_in[3];
    const float* ad1w = (const float*)d_in[4];
    const float* b1   = (const float*)d_in[5];
    const float* W2   = (const float*)d_in[6];
    const float* as2w = (const float*)d_in[7];
    const float* ad2w = (const float*)d_in[8];
    const float* b2   = (const float*)d_in[9];
    float* out = (float*)d_out;

    char* ws = (char*)d_ws;
    float* h1   = (float*)(ws + 0);            // 25,600,000 B
    float* as1  = (float*)(ws + 25600000);     //  3,200,000 B
    float* ad1  = (float*)(ws + 28800000);     //  3,200,000 B
    float* hmid = (float*)(ws + 32000000);     // 25,600,000 B
    float* h2   = (float*)(ws + 57600000);     // 16,000,000 B
    float* as2  = (float*)(ws + 73600000);     //    400,000 B
    float* ad2  = (float*)(ws + 74000000);     //    400,000 B
    int*   deg  = (int*)  (ws + 74400000);     //    400,000 B
    int*   rowp = (int*)  (ws + 74800000);     //    400,004 B
    int*   wofs = (int*)  (ws + 75200256);     //    400,000 B
    int*   esrc = (int*)  (ws + 75600256);     // 13,200,000 B  -> total ~88.8 MB

    hipMemsetAsync(deg, 0, NNODES * sizeof(int), stream);
    k_hist<<<(NTOT + 255) / 256, 256, 0, stream>>>(ei, deg);
    k_scan<<<1, 1024, 0, stream>>>(deg, rowp, wofs);
    k_scatter<<<(NTOT + 255) / 256, 256, 0, stream>>>(ei, wofs, esrc);
    k_gemm1<<<NNODES / 32, 256, 0, stream>>>(x, W1, h1);
    k_att1<<<(NNODES * 8) / 256, 256, 0, stream>>>(h1, as1w, ad1w, as1, ad1);
    k_aggr1<<<NNODES / 4, 256, 0, stream>>>(h1, as1, ad1, rowp, esrc, b1, hmid);
    k_gemm2<<<NNODES / 4, 256, 0, stream>>>(hmid, W2, as2w, ad2w, h2, as2, ad2);
    k_aggr2<<<NNODES / 4, 256, 0, stream>>>(h2, as2, ad2, rowp, esrc, b2, out);
}

// Round 2
// 1066.237 us; speedup vs baseline: 1.3913x; 1.3913x over previous
//
#include <hip/hip_runtime.h>
#include <cstdint>
#include <cstddef>

#define NNODES 100000
#define NEDGES 3200000
#define NTOT   3300000   // edges + self loops
#define FIN    256
#define HH     64        // heads*hid (layer 1 out)
#define NH     8
#define C2     40
#define NEG    0.2f

// ---------------- CSR build ----------------

__global__ __launch_bounds__(256) void k_hist(const int* __restrict__ ei, int* __restrict__ deg) {
    int i = blockIdx.x * 256 + threadIdx.x;
    if (i >= NTOT) return;
    int d = (i < NEDGES) ? ei[NEDGES + i] : (i - NEDGES);
    atomicAdd(&deg[d], 1);
}

__global__ __launch_bounds__(1024) void k_scan(const int* __restrict__ deg, int* __restrict__ rowptr,
                                               int* __restrict__ wofs) {
    __shared__ int part[1024];
    const int CH = 98;  // 1024*98 >= 100000
    int t = threadIdx.x;
    int s0 = t * CH, s1 = s0 + CH;
    if (s1 > NNODES) s1 = NNODES;
    if (s0 > NNODES) s0 = NNODES;
    int s = 0;
    for (int i = s0; i < s1; ++i) s += deg[i];
    part[t] = s;
    __syncthreads();
    for (int off = 1; off < 1024; off <<= 1) {
        int v = (t >= off) ? part[t - off] : 0;
        __syncthreads();
        part[t] += v;
        __syncthreads();
    }
    int run = (t == 0) ? 0 : part[t - 1];
    for (int i = s0; i < s1; ++i) {
        rowptr[i] = run;
        wofs[i] = run;
        run += deg[i];
    }
    if (t == 1023) rowptr[NNODES] = run;
}

__global__ __launch_bounds__(256) void k_scatter(const int* __restrict__ ei, int* __restrict__ wofs,
                                                 int* __restrict__ esrc) {
    int i = blockIdx.x * 256 + threadIdx.x;
    if (i >= NTOT) return;
    int s, d;
    if (i < NEDGES) { s = ei[i]; d = ei[NEDGES + i]; }
    else            { s = d = i - NEDGES; }
    int p = atomicAdd(&wofs[d], 1);
    esrc[p] = s;
}

// ---------------- Layer 1 ----------------

// h1[N,64] = x[N,256] @ W1[256,64]
__global__ __launch_bounds__(256) void k_gemm1(const float* __restrict__ x, const float* __restrict__ W,
                                               float* __restrict__ h1) {
    __shared__ float xs[32][256];
    int t = threadIdx.x;
    size_t n0 = (size_t)blockIdx.x * 32;
    const float4* xg = (const float4*)(x + n0 * FIN);
    float4* xl = (float4*)(&xs[0][0]);
#pragma unroll
    for (int i = 0; i < 8; ++i) xl[t + i * 256] = xg[t + i * 256];
    __syncthreads();
    int c = t & 63, rg = t >> 6;
    float acc[8] = {0.f, 0.f, 0.f, 0.f, 0.f, 0.f, 0.f, 0.f};
    for (int k = 0; k < 256; k += 4) {
        float w0 = W[(k    ) * HH + c];
        float w1 = W[(k + 1) * HH + c];
        float w2 = W[(k + 2) * HH + c];
        float w3 = W[(k + 3) * HH + c];
#pragma unroll
        for (int i = 0; i < 8; ++i) {
            float4 xv = *(const float4*)&xs[rg * 8 + i][k];
            acc[i] = fmaf(xv.x, w0, acc[i]);
            acc[i] = fmaf(xv.y, w1, acc[i]);
            acc[i] = fmaf(xv.z, w2, acc[i]);
            acc[i] = fmaf(xv.w, w3, acc[i]);
        }
    }
#pragma unroll
    for (int i = 0; i < 8; ++i) h1[(n0 + rg * 8 + i) * HH + c] = acc[i];
}

// a_src1/a_dst1 [N,8]
__global__ __launch_bounds__(256) void k_att1(const float* __restrict__ h1, const float* __restrict__ asw,
                                              const float* __restrict__ adw, float* __restrict__ as,
                                              float* __restrict__ ad) {
    int i = blockIdx.x * 256 + threadIdx.x;  // < N*8, exact
    int h = i & 7;
    const float4* hp = (const float4*)(h1 + (size_t)i * 8);
    float4 a = hp[0], b = hp[1];
    const float4* sp = (const float4*)(asw + h * 8);
    const float4* dp = (const float4*)(adw + h * 8);
    float4 s0 = sp[0], s1 = sp[1], d0 = dp[0], d1 = dp[1];
    float sv = a.x * s0.x + a.y * s0.y + a.z * s0.z + a.w * s0.w +
               b.x * s1.x + b.y * s1.y + b.z * s1.z + b.w * s1.w;
    float dv = a.x * d0.x + a.y * d0.y + a.z * d0.z + a.w * d0.w +
               b.x * d1.x + b.y * d1.y + b.z * d1.z + b.w * d1.w;
    as[i] = sv;
    ad[i] = dv;
}

// 2 waves per node (strided halves), 4x unrolled gather; lane t owns channel t (h = t>>3)
__global__ __launch_bounds__(256) void k_aggr1(const float* __restrict__ h1, const float* __restrict__ as,
                                               const float* __restrict__ ad, const int* __restrict__ rowptr,
                                               const int* __restrict__ esrc, const float* __restrict__ b1,
                                               float* __restrict__ hmid) {
    __shared__ float sacc[4][64];
    __shared__ float sden[4][64];
    int wv = threadIdx.x >> 6, t = threadIdx.x & 63;
    int n = blockIdx.x * 2 + (wv >> 1);
    int half = wv & 1;
    int h = t >> 3;
    float adn = ad[n * NH + h];
    int beg = rowptr[n], end = rowptr[n + 1];
    float acc = 0.f, den = 0.f;
    int j = beg + half;
    for (; j + 6 < end; j += 8) {
        int s0 = esrc[j], s1 = esrc[j + 2], s2 = esrc[j + 4], s3 = esrc[j + 6];
        float a0 = as[s0 * NH + h], a1 = as[s1 * NH + h], a2 = as[s2 * NH + h], a3 = as[s3 * NH + h];
        float v0 = h1[(size_t)s0 * HH + t], v1 = h1[(size_t)s1 * HH + t],
              v2 = h1[(size_t)s2 * HH + t], v3 = h1[(size_t)s3 * HH + t];
        float e0 = a0 + adn; e0 = (e0 > 0.f) ? e0 : NEG * e0; float w0 = __expf(e0);
        float e1 = a1 + adn; e1 = (e1 > 0.f) ? e1 : NEG * e1; float w1 = __expf(e1);
        float e2 = a2 + adn; e2 = (e2 > 0.f) ? e2 : NEG * e2; float w2 = __expf(e2);
        float e3 = a3 + adn; e3 = (e3 > 0.f) ? e3 : NEG * e3; float w3 = __expf(e3);
        den += (w0 + w1) + (w2 + w3);
        acc = fmaf(w0, v0, acc);
        acc = fmaf(w1, v1, acc);
        acc = fmaf(w2, v2, acc);
        acc = fmaf(w3, v3, acc);
    }
    for (; j < end; j += 2) {
        int s = esrc[j];
        float e = as[s * NH + h] + adn;
        e = (e > 0.f) ? e : NEG * e;
        float w = __expf(e);
        den += w;
        acc = fmaf(w, h1[(size_t)s * HH + t], acc);
    }
    sacc[wv][t] = acc;
    sden[wv][t] = den;
    __syncthreads();
    if (half == 0) {
        acc += sacc[wv + 1][t];
        den += sden[wv + 1][t];
        float o = acc / (den + 1e-16f) + b1[t];
        hmid[(size_t)n * HH + t] = (o > 0.f) ? o : expm1f(o);  // ELU
    }
}

// ---------------- Layer 2 ----------------

// h2[N,40] = hmid[N,64] @ W2[64,40]; also a_src2/a_dst2 [N]
__global__ __launch_bounds__(256) void k_gemm2(const float* __restrict__ hmid, const float* __restrict__ W2,
                                               const float* __restrict__ as2w, const float* __restrict__ ad2w,
                                               float* __restrict__ h2, float* __restrict__ as2,
                                               float* __restrict__ ad2) {
    __shared__ float w2s[64 * C2];
    __shared__ float hrow[4][64];
    int t = threadIdx.x;
    for (int i = t; i < 64 * C2; i += 256) w2s[i] = W2[i];
    __syncthreads();
    int wv = t >> 6, ln = t & 63;
    int n = blockIdx.x * 4 + wv;
    hrow[wv][ln] = hmid[(size_t)n * HH + ln];
    __syncthreads();
    float acc = 0.f;
    if (ln < C2) {
#pragma unroll 8
        for (int k = 0; k < 64; ++k) acc = fmaf(hrow[wv][k], w2s[k * C2 + ln], acc);
    }
    float sv = 0.f, dv = 0.f;
    if (ln < C2) {
        h2[(size_t)n * C2 + ln] = acc;
        sv = acc * as2w[ln];
        dv = acc * ad2w[ln];
    }
#pragma unroll
    for (int off = 32; off > 0; off >>= 1) {
        sv += __shfl_xor(sv, off);
        dv += __shfl_xor(dv, off);
    }
    if (ln == 0) { as2[n] = sv; ad2[n] = dv; }
}

// 2 waves per node, 4x unrolled; lane t<40 owns class t; fused log_softmax
__global__ __launch_bounds__(256) void k_aggr2(const float* __restrict__ h2, const float* __restrict__ as2,
                                               const float* __restrict__ ad2, const int* __restrict__ rowptr,
                                               const int* __restrict__ esrc, const float* __restrict__ b2,
                                               float* __restrict__ out) {
    __shared__ float sacc[4][64];
    __shared__ float sden[4];
    int wv = threadIdx.x >> 6, t = threadIdx.x & 63;
    int n = blockIdx.x * 2 + (wv >> 1);
    int half = wv & 1;
    float adn = ad2[n];
    int beg = rowptr[n], end = rowptr[n + 1];
    bool act = (t < C2);
    int tc = act ? t : 0;  // clamp: lanes 40..63 duplicate class 0 (same cache line, discarded)
    float acc = 0.f, den = 0.f;
    int j = beg + half;
    for (; j + 6 < end; j += 8) {
        int s0 = esrc[j], s1 = esrc[j + 2], s2 = esrc[j + 4], s3 = esrc[j + 6];
        float a0 = as2[s0], a1 = as2[s1], a2 = as2[s2], a3 = as2[s3];
        float v0 = h2[(size_t)s0 * C2 + tc], v1 = h2[(size_t)s1 * C2 + tc],
              v2 = h2[(size_t)s2 * C2 + tc], v3 = h2[(size_t)s3 * C2 + tc];
        float e0 = a0 + adn; e0 = (e0 > 0.f) ? e0 : NEG * e0; float w0 = __expf(e0);
        float e1 = a1 + adn; e1 = (e1 > 0.f) ? e1 : NEG * e1; float w1 = __expf(e1);
        float e2 = a2 + adn; e2 = (e2 > 0.f) ? e2 : NEG * e2; float w2 = __expf(e2);
        float e3 = a3 + adn; e3 = (e3 > 0.f) ? e3 : NEG * e3; float w3 = __expf(e3);
        den += (w0 + w1) + (w2 + w3);
        acc = fmaf(w0, v0, acc);
        acc = fmaf(w1, v1, acc);
        acc = fmaf(w2, v2, acc);
        acc = fmaf(w3, v3, acc);
    }
    for (; j < end; j += 2) {
        int s = esrc[j];
        float e = as2[s] + adn;
        e = (e > 0.f) ? e : NEG * e;
        float w = __expf(e);
        den += w;
        acc = fmaf(w, h2[(size_t)s * C2 + tc], acc);
    }
    sacc[wv][t] = acc;
    if (t == 0) sden[wv] = den;  // den is lane-uniform
    __syncthreads();
    if (half == 0) {
        float a = sacc[wv][t] + sacc[wv + 1][t];
        float d = sden[wv] + sden[wv + 1];
        float o = act ? (a / (d + 1e-16f) + b2[t]) : -1e30f;
        float m = o;
#pragma unroll
        for (int off = 32; off > 0; off >>= 1) m = fmaxf(m, __shfl_xor(m, off));
        float ex = act ? __expf(o - m) : 0.f;
        float sm = ex;
#pragma unroll
        for (int off = 32; off > 0; off >>= 1) sm += __shfl_xor(sm, off);
        if (act) out[(size_t)n * C2 + t] = o - m - logf(sm);
    }
}

// ---------------- launch ----------------

extern "C" void kernel_launch(void* const* d_in, const int* in_sizes, int n_in,
                              void* d_out, int out_size, void* d_ws, size_t ws_size,
                              hipStream_t stream) {
    const float* x    = (const float*)d_in[0];
    const int*   ei   = (const int*)d_in[1];
    const float* W1   = (const float*)d_in[2];
    const float* as1w = (const float*)d_in[3];
    const float* ad1w = (const float*)d_in[4];
    const float* b1   = (const float*)d_in[5];
    const float* W2   = (const float*)d_in[6];
    const float* as2w = (const float*)d_in[7];
    const float* ad2w = (const float*)d_in[8];
    const float* b2   = (const float*)d_in[9];
    float* out = (float*)d_out;

    char* ws = (char*)d_ws;
    float* h1   = (float*)(ws + 0);            // 25,600,000 B
    float* as1  = (float*)(ws + 25600000);     //  3,200,000 B
    float* ad1  = (float*)(ws + 28800000);     //  3,200,000 B
    float* hmid = (float*)(ws + 32000000);     // 25,600,000 B
    float* h2   = (float*)(ws + 57600000);     // 16,000,000 B
    float* as2  = (float*)(ws + 73600000);     //    400,000 B
    float* ad2  = (float*)(ws + 74000000);     //    400,000 B
    int*   deg  = (int*)  (ws + 74400000);     //    400,000 B
    int*   rowp = (int*)  (ws + 74800000);     //    400,004 B
    int*   wofs = (int*)  (ws + 75200256);     //    400,000 B
    int*   esrc = (int*)  (ws + 75600256);     // 13,200,000 B  -> total ~88.8 MB

    hipMemsetAsync(deg, 0, NNODES * sizeof(int), stream);
    k_hist<<<(NTOT + 255) / 256, 256, 0, stream>>>(ei, deg);
    k_scan<<<1, 1024, 0, stream>>>(deg, rowp, wofs);
    k_scatter<<<(NTOT + 255) / 256, 256, 0, stream>>>(ei, wofs, esrc);
    k_gemm1<<<NNODES / 32, 256, 0, stream>>>(x, W1, h1);
    k_att1<<<(NNODES * 8) / 256, 256, 0, stream>>>(h1, as1w, ad1w, as1, ad1);
    k_aggr1<<<NNODES / 2, 256, 0, stream>>>(h1, as1, ad1, rowp, esrc, b1, hmid);
    k_gemm2<<<NNODES / 4, 256, 0, stream>>>(hmid, W2, as2w, ad2w, h2, as2, ad2);
    k_aggr2<<<NNODES / 2, 256, 0, stream>>>(h2, as2, ad2, rowp, esrc, b2, out);
}

// Round 3
// 581.197 us; speedup vs baseline: 2.5524x; 1.8346x over previous
//
#include <hip/hip_runtime.h>
#include <cstdint>
#include <cstddef>

#define NNODES 100000
#define NEDGES 3200000
#define NTOT   3300000   // edges + self loops
#define FIN    256
#define HH     64        // heads*hid (layer 1 out)
#define NH     8
#define C2     40
#define NEG    0.2f

// counting-sort params
#define CHUNK  8192
#define NBLK   403       // ceil(NTOT/CHUNK)
#define NBKT   391       // ceil(NNODES/256); bucket(d) = d>>8

// ---------------- CSR build: two-level LDS counting sort (no global atomics) ----------------

__global__ __launch_bounds__(256) void k_bhist(const int* __restrict__ ei, int* __restrict__ bhist) {
    __shared__ int h[NBKT];
    int t = threadIdx.x;
    for (int b = t; b < NBKT; b += 256) h[b] = 0;
    __syncthreads();
    int i0 = blockIdx.x * CHUNK;
    int i1 = i0 + CHUNK; if (i1 > NTOT) i1 = NTOT;
    for (int i = i0 + t; i < i1; i += 256) {
        int d = (i < NEDGES) ? ei[NEDGES + i] : (i - NEDGES);
        atomicAdd(&h[d >> 8], 1);      // LDS atomic
    }
    __syncthreads();
    for (int b = t; b < NBKT; b += 256) bhist[b * NBLK + blockIdx.x] = h[b];
}

// per-bucket exclusive scan over blocks; emits bucket totals
__global__ __launch_bounds__(512) void k_bscan(int* __restrict__ bhist, int* __restrict__ bktTot) {
    __shared__ int sm[512];
    int t = threadIdx.x, b = blockIdx.x;
    int v = (t < NBLK) ? bhist[b * NBLK + t] : 0;
    sm[t] = v;
    __syncthreads();
    for (int off = 1; off < 512; off <<= 1) {
        int u = (t >= off) ? sm[t - off] : 0;
        __syncthreads();
        sm[t] += u;
        __syncthreads();
    }
    if (t < NBLK) bhist[b * NBLK + t] = sm[t] - v;   // exclusive prefix within bucket
    if (t == NBLK - 1) bktTot[b] = sm[t];
}

// exclusive scan over bucket totals -> bucket bases
__global__ __launch_bounds__(512) void k_base(const int* __restrict__ bktTot, int* __restrict__ bktBase,
                                              int* __restrict__ rowptr) {
    __shared__ int sm[512];
    int t = threadIdx.x;
    int v = (t < NBKT) ? bktTot[t] : 0;
    sm[t] = v;
    __syncthreads();
    for (int off = 1; off < 512; off <<= 1) {
        int u = (t >= off) ? sm[t - off] : 0;
        __syncthreads();
        sm[t] += u;
        __syncthreads();
    }
    if (t < NBKT) bktBase[t] = sm[t] - v;
    if (t == NBKT - 1) bktBase[NBKT] = sm[t];
    if (t == 0) rowptr[NNODES] = NTOT;
}

// place packed (src<<8 | dst&255) records into bucket-major order via LDS cursors
__global__ __launch_bounds__(256) void k_scat1(const int* __restrict__ ei, const int* __restrict__ bhist,
                                               const int* __restrict__ bktBase, unsigned int* __restrict__ pb) {
    __shared__ int cur[NBKT];
    int t = threadIdx.x, blk = blockIdx.x;
    for (int b = t; b < NBKT; b += 256) cur[b] = bktBase[b] + bhist[b * NBLK + blk];
    __syncthreads();
    int i0 = blk * CHUNK;
    int i1 = i0 + CHUNK; if (i1 > NTOT) i1 = NTOT;
    for (int i = i0 + t; i < i1; i += 256) {
        int s, d;
        if (i < NEDGES) { s = ei[i]; d = ei[NEDGES + i]; }
        else            { s = d = i - NEDGES; }
        int p = atomicAdd(&cur[d >> 8], 1);   // LDS atomic
        pb[p] = ((unsigned)s << 8) | (unsigned)(d & 255);
    }
}

// one WG per bucket: per-node deg + scan + cursors in LDS; write rowptr and final esrc
__global__ __launch_bounds__(256) void k_bucket(const unsigned int* __restrict__ pb,
                                                const int* __restrict__ bktBase,
                                                int* __restrict__ rowptr, int* __restrict__ esrc) {
    __shared__ int dcnt[256];
    __shared__ int sm[256];
    __shared__ int cur[256];
    int t = threadIdx.x, b = blockIdx.x;
    int base = bktBase[b], cnt = bktBase[b + 1] - base;
    dcnt[t] = 0;
    __syncthreads();
    for (int i = t; i < cnt; i += 256) atomicAdd(&dcnt[pb[base + i] & 255], 1);
    __syncthreads();
    int v = dcnt[t];
    sm[t] = v;
    __syncthreads();
    for (int off = 1; off < 256; off <<= 1) {
        int u = (t >= off) ? sm[t - off] : 0;
        __syncthreads();
        sm[t] += u;
        __syncthreads();
    }
    int ex = sm[t] - v;
    int n = (b << 8) + t;
    if (n < NNODES) rowptr[n] = base + ex;
    cur[t] = base + ex;
    __syncthreads();
    for (int i = t; i < cnt; i += 256) {
        unsigned int e = pb[base + i];
        int p = atomicAdd(&cur[e & 255], 1);  // LDS atomic
        esrc[p] = (int)(e >> 8);
    }
}

// ---------------- Layer 1 ----------------

// h1[N,64] = x[N,256] @ W1[256,64]
__global__ __launch_bounds__(256) void k_gemm1(const float* __restrict__ x, const float* __restrict__ W,
                                               float* __restrict__ h1) {
    __shared__ float xs[32][256];
    int t = threadIdx.x;
    size_t n0 = (size_t)blockIdx.x * 32;
    const float4* xg = (const float4*)(x + n0 * FIN);
    float4* xl = (float4*)(&xs[0][0]);
#pragma unroll
    for (int i = 0; i < 8; ++i) xl[t + i * 256] = xg[t + i * 256];
    __syncthreads();
    int c = t & 63, rg = t >> 6;
    float acc[8] = {0.f, 0.f, 0.f, 0.f, 0.f, 0.f, 0.f, 0.f};
    for (int k = 0; k < 256; k += 4) {
        float w0 = W[(k    ) * HH + c];
        float w1 = W[(k + 1) * HH + c];
        float w2 = W[(k + 2) * HH + c];
        float w3 = W[(k + 3) * HH + c];
#pragma unroll
        for (int i = 0; i < 8; ++i) {
            float4 xv = *(const float4*)&xs[rg * 8 + i][k];
            acc[i] = fmaf(xv.x, w0, acc[i]);
            acc[i] = fmaf(xv.y, w1, acc[i]);
            acc[i] = fmaf(xv.z, w2, acc[i]);
            acc[i] = fmaf(xv.w, w3, acc[i]);
        }
    }
#pragma unroll
    for (int i = 0; i < 8; ++i) h1[(n0 + rg * 8 + i) * HH + c] = acc[i];
}

// a_src1/a_dst1 [N,8]
__global__ __launch_bounds__(256) void k_att1(const float* __restrict__ h1, const float* __restrict__ asw,
                                              const float* __restrict__ adw, float* __restrict__ as,
                                              float* __restrict__ ad) {
    int i = blockIdx.x * 256 + threadIdx.x;  // < N*8, exact
    int h = i & 7;
    const float4* hp = (const float4*)(h1 + (size_t)i * 8);
    float4 a = hp[0], b = hp[1];
    const float4* sp = (const float4*)(asw + h * 8);
    const float4* dp = (const float4*)(adw + h * 8);
    float4 s0 = sp[0], s1 = sp[1], d0 = dp[0], d1 = dp[1];
    float sv = a.x * s0.x + a.y * s0.y + a.z * s0.z + a.w * s0.w +
               b.x * s1.x + b.y * s1.y + b.z * s1.z + b.w * s1.w;
    float dv = a.x * d0.x + a.y * d0.y + a.z * d0.z + a.w * d0.w +
               b.x * d1.x + b.y * d1.y + b.z * d1.z + b.w * d1.w;
    as[i] = sv;
    ad[i] = dv;
}

// 4 waves per node (strided quarters), 4x unrolled gather; lane t owns channel t (h = t>>3)
__global__ __launch_bounds__(256) void k_aggr1(const float* __restrict__ h1, const float* __restrict__ as,
                                               const float* __restrict__ ad, const int* __restrict__ rowptr,
                                               const int* __restrict__ esrc, const float* __restrict__ b1,
                                               float* __restrict__ hmid) {
    __shared__ float sacc[4][64];
    __shared__ float sden[4][64];
    int wv = threadIdx.x >> 6, t = threadIdx.x & 63;
    int n = blockIdx.x;
    int h = t >> 3;
    float adn = ad[n * NH + h];
    int beg = rowptr[n], end = rowptr[n + 1];
    float acc = 0.f, den = 0.f;
    int j = beg + wv;
    for (; j + 12 < end; j += 16) {
        int s0 = esrc[j], s1 = esrc[j + 4], s2 = esrc[j + 8], s3 = esrc[j + 12];
        float a0 = as[s0 * NH + h], a1 = as[s1 * NH + h], a2 = as[s2 * NH + h], a3 = as[s3 * NH + h];
        float v0 = h1[(size_t)s0 * HH + t], v1 = h1[(size_t)s1 * HH + t],
              v2 = h1[(size_t)s2 * HH + t], v3 = h1[(size_t)s3 * HH + t];
        float e0 = a0 + adn; e0 = (e0 > 0.f) ? e0 : NEG * e0; float w0 = __expf(e0);
        float e1 = a1 + adn; e1 = (e1 > 0.f) ? e1 : NEG * e1; float w1 = __expf(e1);
        float e2 = a2 + adn; e2 = (e2 > 0.f) ? e2 : NEG * e2; float w2 = __expf(e2);
        float e3 = a3 + adn; e3 = (e3 > 0.f) ? e3 : NEG * e3; float w3 = __expf(e3);
        den += (w0 + w1) + (w2 + w3);
        acc = fmaf(w0, v0, acc);
        acc = fmaf(w1, v1, acc);
        acc = fmaf(w2, v2, acc);
        acc = fmaf(w3, v3, acc);
    }
    for (; j < end; j += 4) {
        int s = esrc[j];
        float e = as[s * NH + h] + adn;
        e = (e > 0.f) ? e : NEG * e;
        float w = __expf(e);
        den += w;
        acc = fmaf(w, h1[(size_t)s * HH + t], acc);
    }
    sacc[wv][t] = acc;
    sden[wv][t] = den;
    __syncthreads();
    if (wv == 0) {
        acc = (acc + sacc[1][t]) + (sacc[2][t] + sacc[3][t]);
        den = (den + sden[1][t]) + (sden[2][t] + sden[3][t]);
        float o = acc / (den + 1e-16f) + b1[t];
        hmid[(size_t)n * HH + t] = (o > 0.f) ? o : expm1f(o);  // ELU
    }
}

// ---------------- Layer 2 ----------------

// h2[N,40] = hmid[N,64] @ W2[64,40]; also a_src2/a_dst2 [N]
__global__ __launch_bounds__(256) void k_gemm2(const float* __restrict__ hmid, const float* __restrict__ W2,
                                               const float* __restrict__ as2w, const float* __restrict__ ad2w,
                                               float* __restrict__ h2, float* __restrict__ as2,
                                               float* __restrict__ ad2) {
    __shared__ float w2s[64 * C2];
    __shared__ float hrow[4][64];
    int t = threadIdx.x;
    for (int i = t; i < 64 * C2; i += 256) w2s[i] = W2[i];
    __syncthreads();
    int wv = t >> 6, ln = t & 63;
    int n = blockIdx.x * 4 + wv;
    hrow[wv][ln] = hmid[(size_t)n * HH + ln];
    __syncthreads();
    float acc = 0.f;
    if (ln < C2) {
#pragma unroll 8
        for (int k = 0; k < 64; ++k) acc = fmaf(hrow[wv][k], w2s[k * C2 + ln], acc);
    }
    float sv = 0.f, dv = 0.f;
    if (ln < C2) {
        h2[(size_t)n * C2 + ln] = acc;
        sv = acc * as2w[ln];
        dv = acc * ad2w[ln];
    }
#pragma unroll
    for (int off = 32; off > 0; off >>= 1) {
        sv += __shfl_xor(sv, off);
        dv += __shfl_xor(dv, off);
    }
    if (ln == 0) { as2[n] = sv; ad2[n] = dv; }
}

// 4 waves per node, 4x unrolled; lane t<40 owns class t; fused log_softmax
__global__ __launch_bounds__(256) void k_aggr2(const float* __restrict__ h2, const float* __restrict__ as2,
                                               const float* __restrict__ ad2, const int* __restrict__ rowptr,
                                               const int* __restrict__ esrc, const float* __restrict__ b2,
                                               float* __restrict__ out) {
    __shared__ float sacc[4][64];
    __shared__ float sden[4];
    int wv = threadIdx.x >> 6, t = threadIdx.x & 63;
    int n = blockIdx.x;
    float adn = ad2[n];
    int beg = rowptr[n], end = rowptr[n + 1];
    bool act = (t < C2);
    int tc = act ? t : 0;  // clamp: lanes 40..63 duplicate class 0 (same cache line, discarded)
    float acc = 0.f, den = 0.f;
    int j = beg + wv;
    for (; j + 12 < end; j += 16) {
        int s0 = esrc[j], s1 = esrc[j + 4], s2 = esrc[j + 8], s3 = esrc[j + 12];
        float a0 = as2[s0], a1 = as2[s1], a2 = as2[s2], a3 = as2[s3];
        float v0 = h2[(size_t)s0 * C2 + tc], v1 = h2[(size_t)s1 * C2 + tc],
              v2 = h2[(size_t)s2 * C2 + tc], v3 = h2[(size_t)s3 * C2 + tc];
        float e0 = a0 + adn; e0 = (e0 > 0.f) ? e0 : NEG * e0; float w0 = __expf(e0);
        float e1 = a1 + adn; e1 = (e1 > 0.f) ? e1 : NEG * e1; float w1 = __expf(e1);
        float e2 = a2 + adn; e2 = (e2 > 0.f) ? e2 : NEG * e2; float w2 = __expf(e2);
        float e3 = a3 + adn; e3 = (e3 > 0.f) ? e3 : NEG * e3; float w3 = __expf(e3);
        den += (w0 + w1) + (w2 + w3);
        acc = fmaf(w0, v0, acc);
        acc = fmaf(w1, v1, acc);
        acc = fmaf(w2, v2, acc);
        acc = fmaf(w3, v3, acc);
    }
    for (; j < end; j += 4) {
        int s = esrc[j];
        float e = as2[s] + adn;
        e = (e > 0.f) ? e : NEG * e;
        float w = __expf(e);
        den += w;
        acc = fmaf(w, h2[(size_t)s * C2 + tc], acc);
    }
    sacc[wv][t] = acc;
    if (t == 0) sden[wv] = den;  // den is lane-uniform
    __syncthreads();
    if (wv == 0) {
        float a = (acc + sacc[1][t]) + (sacc[2][t] + sacc[3][t]);
        float d = (sden[0] + sden[1]) + (sden[2] + sden[3]);
        float o = act ? (a / (d + 1e-16f) + b2[t]) : -1e30f;
        float m = o;
#pragma unroll
        for (int off = 32; off > 0; off >>= 1) m = fmaxf(m, __shfl_xor(m, off));
        float ex = act ? __expf(o - m) : 0.f;
        float sm = ex;
#pragma unroll
        for (int off = 32; off > 0; off >>= 1) sm += __shfl_xor(sm, off);
        if (act) out[(size_t)n * C2 + t] = o - m - logf(sm);
    }
}

// ---------------- launch ----------------

extern "C" void kernel_launch(void* const* d_in, const int* in_sizes, int n_in,
                              void* d_out, int out_size, void* d_ws, size_t ws_size,
                              hipStream_t stream) {
    const float* x    = (const float*)d_in[0];
    const int*   ei   = (const int*)d_in[1];
    const float* W1   = (const float*)d_in[2];
    const float* as1w = (const float*)d_in[3];
    const float* ad1w = (const float*)d_in[4];
    const float* b1   = (const float*)d_in[5];
    const float* W2   = (const float*)d_in[6];
    const float* as2w = (const float*)d_in[7];
    const float* ad2w = (const float*)d_in[8];
    const float* b2   = (const float*)d_in[9];
    float* out = (float*)d_out;

    // workspace layout (aliasing: bhist->hmid region, pb->h2 region, bktBase->as2, bktTot->ad2;
    // all CSR-build temporaries are dead before their alias partners are written)
    char* ws = (char*)d_ws;
    float* h1      = (float*)(ws + 0);            // 25,600,000 B
    float* as1     = (float*)(ws + 25600000);     //  3,200,000 B
    float* ad1     = (float*)(ws + 28800000);     //  3,200,000 B
    float* hmid    = (float*)(ws + 32000000);     // 25,600,000 B
    int*   bhist   = (int*)  (ws + 32000000);     //    630,292 B (alias hmid; dead after k_scat1)
    float* h2      = (float*)(ws + 57600000);     // 16,000,000 B
    unsigned int* pb = (unsigned int*)(ws + 57600000); // 13,200,000 B (alias h2; dead after k_bucket)
    float* as2     = (float*)(ws + 73600000);     //    400,000 B
    int*   bktBase = (int*)  (ws + 73600000);     //      1,568 B (alias as2; dead after k_bucket)
    float* ad2     = (float*)(ws + 74000000);     //    400,000 B
    int*   bktTot  = (int*)  (ws + 74000000);     //      1,564 B (alias ad2; dead after k_base)
    int*   rowp    = (int*)  (ws + 74800000);     //    400,004 B
    int*   esrc    = (int*)  (ws + 75600256);     // 13,200,000 B  -> total ~88.8 MB

    k_bhist <<<NBLK, 256, 0, stream>>>(ei, bhist);
    k_bscan <<<NBKT, 512, 0, stream>>>(bhist, bktTot);
    k_base  <<<1,    512, 0, stream>>>(bktTot, bktBase, rowp);
    k_scat1 <<<NBLK, 256, 0, stream>>>(ei, bhist, bktBase, pb);
    k_bucket<<<NBKT, 256, 0, stream>>>(pb, bktBase, rowp, esrc);
    k_gemm1 <<<NNODES / 32, 256, 0, stream>>>(x, W1, h1);
    k_att1  <<<(NNODES * 8) / 256, 256, 0, stream>>>(h1, as1w, ad1w, as1, ad1);
    k_aggr1 <<<NNODES, 256, 0, stream>>>(h1, as1, ad1, rowp, esrc, b1, hmid);
    k_gemm2 <<<NNODES / 4, 256, 0, stream>>>(hmid, W2, as2w, ad2w, h2, as2, ad2);
    k_aggr2 <<<NNODES, 256, 0, stream>>>(h2, as2, ad2, rowp, esrc, b2, out);
}

// Round 4
// 494.804 us; speedup vs baseline: 2.9981x; 1.1746x over previous
//
#include <hip/hip_runtime.h>
#include <hip/hip_bf16.h>
#include <cstdint>
#include <cstddef>

#define NNODES 100000
#define NEDGES 3200000
#define NTOT   3300000   // edges + self loops
#define FIN    256
#define HH     64        // heads*hid (layer 1 out)
#define NH     8
#define C2     40
#define NEG    0.2f

// counting-sort params
#define CHUNK  8192
#define NBLK   403       // ceil(NTOT/CHUNK)
#define NBKT   391       // ceil(NNODES/256); bucket(d) = d>>8

typedef __hip_bfloat16 bf16;

// ---------------- CSR build: two-level LDS counting sort (no global atomics) ----------------

__global__ __launch_bounds__(256) void k_bhist(const int* __restrict__ ei, int* __restrict__ bhist) {
    __shared__ int h[NBKT];
    int t = threadIdx.x;
    for (int b = t; b < NBKT; b += 256) h[b] = 0;
    __syncthreads();
    int i0 = blockIdx.x * CHUNK;
    int i1 = i0 + CHUNK; if (i1 > NTOT) i1 = NTOT;
    for (int i = i0 + t; i < i1; i += 256) {
        int d = (i < NEDGES) ? ei[NEDGES + i] : (i - NEDGES);
        atomicAdd(&h[d >> 8], 1);      // LDS atomic
    }
    __syncthreads();
    for (int b = t; b < NBKT; b += 256) bhist[b * NBLK + blockIdx.x] = h[b];
}

// per-bucket exclusive scan over blocks; emits bucket totals
__global__ __launch_bounds__(512) void k_bscan(int* __restrict__ bhist, int* __restrict__ bktTot) {
    __shared__ int sm[512];
    int t = threadIdx.x, b = blockIdx.x;
    int v = (t < NBLK) ? bhist[b * NBLK + t] : 0;
    sm[t] = v;
    __syncthreads();
    for (int off = 1; off < 512; off <<= 1) {
        int u = (t >= off) ? sm[t - off] : 0;
        __syncthreads();
        sm[t] += u;
        __syncthreads();
    }
    if (t < NBLK) bhist[b * NBLK + t] = sm[t] - v;   // exclusive prefix within bucket
    if (t == NBLK - 1) bktTot[b] = sm[t];
}

// exclusive scan over bucket totals -> bucket bases
__global__ __launch_bounds__(512) void k_base(const int* __restrict__ bktTot, int* __restrict__ bktBase,
                                              int* __restrict__ rowptr) {
    __shared__ int sm[512];
    int t = threadIdx.x;
    int v = (t < NBKT) ? bktTot[t] : 0;
    sm[t] = v;
    __syncthreads();
    for (int off = 1; off < 512; off <<= 1) {
        int u = (t >= off) ? sm[t - off] : 0;
        __syncthreads();
        sm[t] += u;
        __syncthreads();
    }
    if (t < NBKT) bktBase[t] = sm[t] - v;
    if (t == NBKT - 1) bktBase[NBKT] = sm[t];
    if (t == 0) rowptr[NNODES] = NTOT;
}

// place packed (src<<8 | dst&255) records into bucket-major order via LDS cursors
__global__ __launch_bounds__(256) void k_scat1(const int* __restrict__ ei, const int* __restrict__ bhist,
                                               const int* __restrict__ bktBase, unsigned int* __restrict__ pb) {
    __shared__ int cur[NBKT];
    int t = threadIdx.x, blk = blockIdx.x;
    for (int b = t; b < NBKT; b += 256) cur[b] = bktBase[b] + bhist[b * NBLK + blk];
    __syncthreads();
    int i0 = blk * CHUNK;
    int i1 = i0 + CHUNK; if (i1 > NTOT) i1 = NTOT;
    for (int i = i0 + t; i < i1; i += 256) {
        int s, d;
        if (i < NEDGES) { s = ei[i]; d = ei[NEDGES + i]; }
        else            { s = d = i - NEDGES; }
        int p = atomicAdd(&cur[d >> 8], 1);   // LDS atomic
        pb[p] = ((unsigned)s << 8) | (unsigned)(d & 255);
    }
}

// one WG per bucket: per-node deg + scan + cursors in LDS; write rowptr and final esrc
__global__ __launch_bounds__(256) void k_bucket(const unsigned int* __restrict__ pb,
                                                const int* __restrict__ bktBase,
                                                int* __restrict__ rowptr, int* __restrict__ esrc) {
    __shared__ int dcnt[256];
    __shared__ int sm[256];
    __shared__ int cur[256];
    int t = threadIdx.x, b = blockIdx.x;
    int base = bktBase[b], cnt = bktBase[b + 1] - base;
    dcnt[t] = 0;
    __syncthreads();
    for (int i = t; i < cnt; i += 256) atomicAdd(&dcnt[pb[base + i] & 255], 1);
    __syncthreads();
    int v = dcnt[t];
    sm[t] = v;
    __syncthreads();
    for (int off = 1; off < 256; off <<= 1) {
        int u = (t >= off) ? sm[t - off] : 0;
        __syncthreads();
        sm[t] += u;
        __syncthreads();
    }
    int ex = sm[t] - v;
    int n = (b << 8) + t;
    if (n < NNODES) rowptr[n] = base + ex;
    cur[t] = base + ex;
    __syncthreads();
    for (int i = t; i < cnt; i += 256) {
        unsigned int e = pb[base + i];
        int p = atomicAdd(&cur[e & 255], 1);  // LDS atomic
        esrc[p] = (int)(e >> 8);
    }
}

// ---------------- Layer 1 ----------------

// h1b[N,64](bf16) = x[N,256] @ W1[256,64]; fused per-head attention dots -> as/ad [N,8] (f32)
__global__ __launch_bounds__(256) void k_gemm1(const float* __restrict__ x, const float* __restrict__ W,
                                               const float* __restrict__ asw, const float* __restrict__ adw,
                                               bf16* __restrict__ h1b, float* __restrict__ as,
                                               float* __restrict__ ad) {
    __shared__ float xs[32][256];
    int t = threadIdx.x;
    size_t n0 = (size_t)blockIdx.x * 32;
    const float4* xg = (const float4*)(x + n0 * FIN);
    float4* xl = (float4*)(&xs[0][0]);
#pragma unroll
    for (int i = 0; i < 8; ++i) xl[t + i * 256] = xg[t + i * 256];
    __syncthreads();
    int c = t & 63, rg = t >> 6;
    float acc[8] = {0.f, 0.f, 0.f, 0.f, 0.f, 0.f, 0.f, 0.f};
    for (int k = 0; k < 256; k += 4) {
        float w0 = W[(k    ) * HH + c];
        float w1 = W[(k + 1) * HH + c];
        float w2 = W[(k + 2) * HH + c];
        float w3 = W[(k + 3) * HH + c];
#pragma unroll
        for (int i = 0; i < 8; ++i) {
            float4 xv = *(const float4*)&xs[rg * 8 + i][k];
            acc[i] = fmaf(xv.x, w0, acc[i]);
            acc[i] = fmaf(xv.y, w1, acc[i]);
            acc[i] = fmaf(xv.z, w2, acc[i]);
            acc[i] = fmaf(xv.w, w3, acc[i]);
        }
    }
    float aw = asw[c], dw = adw[c];  // att_src1/att_dst1 flat [64]: head=c>>3, ch=c&7
#pragma unroll
    for (int i = 0; i < 8; ++i) {
        int n = (int)n0 + rg * 8 + i;
        h1b[(size_t)n * HH + c] = __float2bfloat16(acc[i]);
        float sv = acc[i] * aw, dv = acc[i] * dw;
        sv += __shfl_xor(sv, 1); sv += __shfl_xor(sv, 2); sv += __shfl_xor(sv, 4);
        dv += __shfl_xor(dv, 1); dv += __shfl_xor(dv, 2); dv += __shfl_xor(dv, 4);
        if ((t & 7) == 0) {
            as[n * NH + (c >> 3)] = sv;
            ad[n * NH + (c >> 3)] = dv;
        }
    }
}

// 4 waves per node (strided quarters), 4x unrolled gather; lane t owns channel t (h = t>>3)
// scalarized edge walk: esrc values forced to SGPRs -> SALU row addressing
__global__ __launch_bounds__(256) void k_aggr1(const bf16* __restrict__ h1b, const float* __restrict__ as,
                                               const float* __restrict__ ad, const int* __restrict__ rowptr,
                                               const int* __restrict__ esrc, const float* __restrict__ b1,
                                               float* __restrict__ hmid) {
    __shared__ float sacc[4][64];
    __shared__ float sden[4][64];
    int wv = __builtin_amdgcn_readfirstlane(threadIdx.x >> 6), t = threadIdx.x & 63;
    int n = blockIdx.x;
    int h = t >> 3;
    float adn = ad[n * NH + h];
    int beg = __builtin_amdgcn_readfirstlane(rowptr[n]);
    int end = __builtin_amdgcn_readfirstlane(rowptr[n + 1]);
    float acc = 0.f, den = 0.f;
    int j = beg + wv;
    for (; j + 12 < end; j += 16) {
        int s0 = __builtin_amdgcn_readfirstlane(esrc[j]);
        int s1 = __builtin_amdgcn_readfirstlane(esrc[j + 4]);
        int s2 = __builtin_amdgcn_readfirstlane(esrc[j + 8]);
        int s3 = __builtin_amdgcn_readfirstlane(esrc[j + 12]);
        float a0 = as[s0 * NH + h], a1 = as[s1 * NH + h], a2 = as[s2 * NH + h], a3 = as[s3 * NH + h];
        float v0 = __bfloat162float(h1b[(size_t)s0 * HH + t]);
        float v1 = __bfloat162float(h1b[(size_t)s1 * HH + t]);
        float v2 = __bfloat162float(h1b[(size_t)s2 * HH + t]);
        float v3 = __bfloat162float(h1b[(size_t)s3 * HH + t]);
        float e0 = a0 + adn; e0 = (e0 > 0.f) ? e0 : NEG * e0; float w0 = __expf(e0);
        float e1 = a1 + adn; e1 = (e1 > 0.f) ? e1 : NEG * e1; float w1 = __expf(e1);
        float e2 = a2 + adn; e2 = (e2 > 0.f) ? e2 : NEG * e2; float w2 = __expf(e2);
        float e3 = a3 + adn; e3 = (e3 > 0.f) ? e3 : NEG * e3; float w3 = __expf(e3);
        den += (w0 + w1) + (w2 + w3);
        acc = fmaf(w0, v0, acc);
        acc = fmaf(w1, v1, acc);
        acc = fmaf(w2, v2, acc);
        acc = fmaf(w3, v3, acc);
    }
    for (; j < end; j += 4) {
        int s = __builtin_amdgcn_readfirstlane(esrc[j]);
        float e = as[s * NH + h] + adn;
        e = (e > 0.f) ? e : NEG * e;
        float w = __expf(e);
        den += w;
        acc = fmaf(w, __bfloat162float(h1b[(size_t)s * HH + t]), acc);
    }
    sacc[wv][t] = acc;
    sden[wv][t] = den;
    __syncthreads();
    if (wv == 0) {
        acc = (acc + sacc[1][t]) + (sacc[2][t] + sacc[3][t]);
        den = (den + sden[1][t]) + (sden[2][t] + sden[3][t]);
        float o = acc / (den + 1e-16f) + b1[t];
        hmid[(size_t)n * HH + t] = (o > 0.f) ? o : expm1f(o);  // ELU
    }
}

// ---------------- Layer 2 ----------------

// h2b[N,40](bf16) = hmid[N,64] @ W2[64,40]; also a_src2/a_dst2 [N] (f32, from f32 acc)
__global__ __launch_bounds__(256) void k_gemm2(const float* __restrict__ hmid, const float* __restrict__ W2,
                                               const float* __restrict__ as2w, const float* __restrict__ ad2w,
                                               bf16* __restrict__ h2b, float* __restrict__ as2,
                                               float* __restrict__ ad2) {
    __shared__ float w2s[64 * C2];
    __shared__ float hrow[4][64];
    int t = threadIdx.x;
    for (int i = t; i < 64 * C2; i += 256) w2s[i] = W2[i];
    __syncthreads();
    int wv = t >> 6, ln = t & 63;
    int n = blockIdx.x * 4 + wv;
    hrow[wv][ln] = hmid[(size_t)n * HH + ln];
    __syncthreads();
    float acc = 0.f;
    if (ln < C2) {
#pragma unroll 8
        for (int k = 0; k < 64; ++k) acc = fmaf(hrow[wv][k], w2s[k * C2 + ln], acc);
    }
    float sv = 0.f, dv = 0.f;
    if (ln < C2) {
        h2b[(size_t)n * C2 + ln] = __float2bfloat16(acc);
        sv = acc * as2w[ln];
        dv = acc * ad2w[ln];
    }
#pragma unroll
    for (int off = 32; off > 0; off >>= 1) {
        sv += __shfl_xor(sv, off);
        dv += __shfl_xor(dv, off);
    }
    if (ln == 0) { as2[n] = sv; ad2[n] = dv; }
}

// 4 waves per node, 4x unrolled, scalarized; lane t<40 owns class t; fused log_softmax
__global__ __launch_bounds__(256) void k_aggr2(const bf16* __restrict__ h2b, const float* __restrict__ as2,
                                               const float* __restrict__ ad2, const int* __restrict__ rowptr,
                                               const int* __restrict__ esrc, const float* __restrict__ b2,
                                               float* __restrict__ out) {
    __shared__ float sacc[4][64];
    __shared__ float sden[4];
    int wv = __builtin_amdgcn_readfirstlane(threadIdx.x >> 6), t = threadIdx.x & 63;
    int n = blockIdx.x;
    float adn = ad2[n];
    int beg = __builtin_amdgcn_readfirstlane(rowptr[n]);
    int end = __builtin_amdgcn_readfirstlane(rowptr[n + 1]);
    bool act = (t < C2);
    int tc = act ? t : 0;  // clamp: lanes 40..63 duplicate class 0 (discarded)
    float acc = 0.f, den = 0.f;
    int j = beg + wv;
    for (; j + 12 < end; j += 16) {
        int s0 = __builtin_amdgcn_readfirstlane(esrc[j]);
        int s1 = __builtin_amdgcn_readfirstlane(esrc[j + 4]);
        int s2 = __builtin_amdgcn_readfirstlane(esrc[j + 8]);
        int s3 = __builtin_amdgcn_readfirstlane(esrc[j + 12]);
        float a0 = as2[s0], a1 = as2[s1], a2 = as2[s2], a3 = as2[s3];
        float v0 = __bfloat162float(h2b[(size_t)s0 * C2 + tc]);
        float v1 = __bfloat162float(h2b[(size_t)s1 * C2 + tc]);
        float v2 = __bfloat162float(h2b[(size_t)s2 * C2 + tc]);
        float v3 = __bfloat162float(h2b[(size_t)s3 * C2 + tc]);
        float e0 = a0 + adn; e0 = (e0 > 0.f) ? e0 : NEG * e0; float w0 = __expf(e0);
        float e1 = a1 + adn; e1 = (e1 > 0.f) ? e1 : NEG * e1; float w1 = __expf(e1);
        float e2 = a2 + adn; e2 = (e2 > 0.f) ? e2 : NEG * e2; float w2 = __expf(e2);
        float e3 = a3 + adn; e3 = (e3 > 0.f) ? e3 : NEG * e3; float w3 = __expf(e3);
        den += (w0 + w1) + (w2 + w3);
        acc = fmaf(w0, v0, acc);
        acc = fmaf(w1, v1, acc);
        acc = fmaf(w2, v2, acc);
        acc = fmaf(w3, v3, acc);
    }
    for (; j < end; j += 4) {
        int s = __builtin_amdgcn_readfirstlane(esrc[j]);
        float e = as2[s] + adn;
        e = (e > 0.f) ? e : NEG * e;
        float w = __expf(e);
        den += w;
        acc = fmaf(w, __bfloat162float(h2b[(size_t)s * C2 + tc]), acc);
    }
    sacc[wv][t] = acc;
    if (t == 0) sden[wv] = den;  // den is lane-uniform
    __syncthreads();
    if (wv == 0) {
        float a = (acc + sacc[1][t]) + (sacc[2][t] + sacc[3][t]);
        float d = (sden[0] + sden[1]) + (sden[2] + sden[3]);
        float o = act ? (a / (d + 1e-16f) + b2[t]) : -1e30f;
        float m = o;
#pragma unroll
        for (int off = 32; off > 0; off >>= 1) m = fmaxf(m, __shfl_xor(m, off));
        float ex = act ? __expf(o - m) : 0.f;
        float sm = ex;
#pragma unroll
        for (int off = 32; off > 0; off >>= 1) sm += __shfl_xor(sm, off);
        if (act) out[(size_t)n * C2 + t] = o - m - logf(sm);
    }
}

// ---------------- launch ----------------

extern "C" void kernel_launch(void* const* d_in, const int* in_sizes, int n_in,
                              void* d_out, int out_size, void* d_ws, size_t ws_size,
                              hipStream_t stream) {
    const float* x    = (const float*)d_in[0];
    const int*   ei   = (const int*)d_in[1];
    const float* W1   = (const float*)d_in[2];
    const float* as1w = (const float*)d_in[3];
    const float* ad1w = (const float*)d_in[4];
    const float* b1   = (const float*)d_in[5];
    const float* W2   = (const float*)d_in[6];
    const float* as2w = (const float*)d_in[7];
    const float* ad2w = (const float*)d_in[8];
    const float* b2   = (const float*)d_in[9];
    float* out = (float*)d_out;

    // workspace layout; CSR temporaries alias later-written buffers (all CSR kernels
    // complete before the aliased partner is first written, same stream)
    char* ws = (char*)d_ws;
    bf16*  h1b     = (bf16*) (ws + 0);            // 12,800,000 B
    float* as1     = (float*)(ws + 12800000);     //  3,200,000 B
    float* ad1     = (float*)(ws + 16000000);     //  3,200,000 B
    float* hmid    = (float*)(ws + 19200000);     // 25,600,000 B
    unsigned int* pb = (unsigned int*)(ws + 19200000); // 13,200,000 B (alias hmid; dead after k_bucket)
    bf16*  h2b     = (bf16*) (ws + 44800000);     //  8,000,000 B
    int*   bhist   = (int*)  (ws + 44800000);     //    630,292 B (alias h2b; dead after k_scat1)
    float* as2     = (float*)(ws + 52800000);     //    400,000 B
    int*   bktBase = (int*)  (ws + 52800000);     //      1,568 B (alias as2; dead after k_bucket)
    float* ad2     = (float*)(ws + 53200000);     //    400,000 B
    int*   bktTot  = (int*)  (ws + 53200000);     //      1,564 B (alias ad2; dead after k_base)
    int*   rowp    = (int*)  (ws + 53600000);     //    400,004 B
    int*   esrc    = (int*)  (ws + 54000256);     // 13,200,000 B -> total ~67.2 MB

    k_bhist <<<NBLK, 256, 0, stream>>>(ei, bhist);
    k_bscan <<<NBKT, 512, 0, stream>>>(bhist, bktTot);
    k_base  <<<1,    512, 0, stream>>>(bktTot, bktBase, rowp);
    k_scat1 <<<NBLK, 256, 0, stream>>>(ei, bhist, bktBase, pb);
    k_bucket<<<NBKT, 256, 0, stream>>>(pb, bktBase, rowp, esrc);
    k_gemm1 <<<NNODES / 32, 256, 0, stream>>>(x, W1, as1w, ad1w, h1b, as1, ad1);
    k_aggr1 <<<NNODES, 256, 0, stream>>>(h1b, as1, ad1, rowp, esrc, b1, hmid);
    k_gemm2 <<<NNODES / 4, 256, 0, stream>>>(hmid, W2, as2w, ad2w, h2b, as2, ad2);
    k_aggr2 <<<NNODES, 256, 0, stream>>>(h2b, as2, ad2, rowp, esrc, b2, out);
}

// Round 5
// 413.999 us; speedup vs baseline: 3.5833x; 1.1952x over previous
//
#include <hip/hip_runtime.h>
#include <hip/hip_bf16.h>
#include <cstdint>
#include <cstddef>

#define NNODES 100000
#define NEDGES 3200000
#define NTOT   3300000   // edges + self loops
#define FIN    256
#define HH     64        // heads*hid (layer 1 out)
#define NH     8
#define C2     40
#define NEG    0.2f

// counting-sort params
#define CHUNK  8192
#define NBLK   403       // ceil(NTOT/CHUNK)
#define NBKT   391       // ceil(NNODES/256); bucket(d) = d>>8

typedef __hip_bfloat16 bf16;

// ---------------- CSR build: two-level LDS counting sort (no global atomics) ----------------

__global__ __launch_bounds__(256) void k_bhist(const int* __restrict__ ei, int* __restrict__ bhist) {
    __shared__ int h[NBKT];
    int t = threadIdx.x;
    for (int b = t; b < NBKT; b += 256) h[b] = 0;
    __syncthreads();
    int i0 = blockIdx.x * CHUNK;
    int i1 = i0 + CHUNK; if (i1 > NTOT) i1 = NTOT;
    for (int i = i0 + t; i < i1; i += 256) {
        int d = (i < NEDGES) ? ei[NEDGES + i] : (i - NEDGES);
        atomicAdd(&h[d >> 8], 1);      // LDS atomic
    }
    __syncthreads();
    for (int b = t; b < NBKT; b += 256) bhist[b * NBLK + blockIdx.x] = h[b];
}

// per-bucket exclusive scan over blocks; emits bucket totals
__global__ __launch_bounds__(512) void k_bscan(int* __restrict__ bhist, int* __restrict__ bktTot) {
    __shared__ int sm[512];
    int t = threadIdx.x, b = blockIdx.x;
    int v = (t < NBLK) ? bhist[b * NBLK + t] : 0;
    sm[t] = v;
    __syncthreads();
    for (int off = 1; off < 512; off <<= 1) {
        int u = (t >= off) ? sm[t - off] : 0;
        __syncthreads();
        sm[t] += u;
        __syncthreads();
    }
    if (t < NBLK) bhist[b * NBLK + t] = sm[t] - v;   // exclusive prefix within bucket
    if (t == NBLK - 1) bktTot[b] = sm[t];
}

// exclusive scan over bucket totals -> bucket bases
__global__ __launch_bounds__(512) void k_base(const int* __restrict__ bktTot, int* __restrict__ bktBase,
                                              int* __restrict__ rowptr) {
    __shared__ int sm[512];
    int t = threadIdx.x;
    int v = (t < NBKT) ? bktTot[t] : 0;
    sm[t] = v;
    __syncthreads();
    for (int off = 1; off < 512; off <<= 1) {
        int u = (t >= off) ? sm[t - off] : 0;
        __syncthreads();
        sm[t] += u;
        __syncthreads();
    }
    if (t < NBKT) bktBase[t] = sm[t] - v;
    if (t == NBKT - 1) bktBase[NBKT] = sm[t];
    if (t == 0) rowptr[NNODES] = NTOT;
}

// place packed (src<<8 | dst&255) records into bucket-major order via LDS cursors
__global__ __launch_bounds__(256) void k_scat1(const int* __restrict__ ei, const int* __restrict__ bhist,
                                               const int* __restrict__ bktBase, unsigned int* __restrict__ pb) {
    __shared__ int cur[NBKT];
    int t = threadIdx.x, blk = blockIdx.x;
    for (int b = t; b < NBKT; b += 256) cur[b] = bktBase[b] + bhist[b * NBLK + blk];
    __syncthreads();
    int i0 = blk * CHUNK;
    int i1 = i0 + CHUNK; if (i1 > NTOT) i1 = NTOT;
    for (int i = i0 + t; i < i1; i += 256) {
        int s, d;
        if (i < NEDGES) { s = ei[i]; d = ei[NEDGES + i]; }
        else            { s = d = i - NEDGES; }
        int p = atomicAdd(&cur[d >> 8], 1);   // LDS atomic
        pb[p] = ((unsigned)s << 8) | (unsigned)(d & 255);
    }
}

// one WG per bucket: per-node deg + scan + cursors in LDS; write rowptr and final esrc
__global__ __launch_bounds__(256) void k_bucket(const unsigned int* __restrict__ pb,
                                                const int* __restrict__ bktBase,
                                                int* __restrict__ rowptr, int* __restrict__ esrc) {
    __shared__ int dcnt[256];
    __shared__ int sm[256];
    __shared__ int cur[256];
    int t = threadIdx.x, b = blockIdx.x;
    int base = bktBase[b], cnt = bktBase[b + 1] - base;
    dcnt[t] = 0;
    __syncthreads();
    for (int i = t; i < cnt; i += 256) atomicAdd(&dcnt[pb[base + i] & 255], 1);
    __syncthreads();
    int v = dcnt[t];
    sm[t] = v;
    __syncthreads();
    for (int off = 1; off < 256; off <<= 1) {
        int u = (t >= off) ? sm[t - off] : 0;
        __syncthreads();
        sm[t] += u;
        __syncthreads();
    }
    int ex = sm[t] - v;
    int n = (b << 8) + t;
    if (n < NNODES) rowptr[n] = base + ex;
    cur[t] = base + ex;
    __syncthreads();
    for (int i = t; i < cnt; i += 256) {
        unsigned int e = pb[base + i];
        int p = atomicAdd(&cur[e & 255], 1);  // LDS atomic
        esrc[p] = (int)(e >> 8);
    }
}

// ---------------- Layer 1 ----------------

// h1b[N,64](bf16) = x[N,256] @ W1[256,64]; fused per-head attention dots -> as/ad [N,8] (f32)
__global__ __launch_bounds__(256) void k_gemm1(const float* __restrict__ x, const float* __restrict__ W,
                                               const float* __restrict__ asw, const float* __restrict__ adw,
                                               bf16* __restrict__ h1b, float* __restrict__ as,
                                               float* __restrict__ ad) {
    __shared__ float xs[32][256];
    int t = threadIdx.x;
    size_t n0 = (size_t)blockIdx.x * 32;
    const float4* xg = (const float4*)(x + n0 * FIN);
    float4* xl = (float4*)(&xs[0][0]);
#pragma unroll
    for (int i = 0; i < 8; ++i) xl[t + i * 256] = xg[t + i * 256];
    __syncthreads();
    int c = t & 63, rg = t >> 6;
    float acc[8] = {0.f, 0.f, 0.f, 0.f, 0.f, 0.f, 0.f, 0.f};
    for (int k = 0; k < 256; k += 4) {
        float w0 = W[(k    ) * HH + c];
        float w1 = W[(k + 1) * HH + c];
        float w2 = W[(k + 2) * HH + c];
        float w3 = W[(k + 3) * HH + c];
#pragma unroll
        for (int i = 0; i < 8; ++i) {
            float4 xv = *(const float4*)&xs[rg * 8 + i][k];
            acc[i] = fmaf(xv.x, w0, acc[i]);
            acc[i] = fmaf(xv.y, w1, acc[i]);
            acc[i] = fmaf(xv.z, w2, acc[i]);
            acc[i] = fmaf(xv.w, w3, acc[i]);
        }
    }
    float aw = asw[c], dw = adw[c];  // att_src1/att_dst1 flat [64]: head=c>>3, ch=c&7
#pragma unroll
    for (int i = 0; i < 8; ++i) {
        int n = (int)n0 + rg * 8 + i;
        h1b[(size_t)n * HH + c] = __float2bfloat16(acc[i]);
        float sv = acc[i] * aw, dv = acc[i] * dw;
        sv += __shfl_xor(sv, 1); sv += __shfl_xor(sv, 2); sv += __shfl_xor(sv, 4);
        dv += __shfl_xor(dv, 1); dv += __shfl_xor(dv, 2); dv += __shfl_xor(dv, 4);
        if ((t & 7) == 0) {
            as[n * NH + (c >> 3)] = sv;
            ad[n * NH + (c >> 3)] = dv;
        }
    }
}

// one wave per node; batch of 8 edges x 8 heads in e-phase, shuffle-broadcast in fma-phase
__global__ __launch_bounds__(256) void k_aggr1(const bf16* __restrict__ h1b, const float* __restrict__ as,
                                               const float* __restrict__ ad, const int* __restrict__ rowptr,
                                               const int* __restrict__ esrc, const float* __restrict__ b1,
                                               float* __restrict__ hmid) {
    int wv = __builtin_amdgcn_readfirstlane(threadIdx.x >> 6);
    int t = threadIdx.x & 63;
    int n = blockIdx.x * 4 + wv;
    int ih = t & 7;   // e-phase: head this lane evaluates
    int ie = t >> 3;  // e-phase: edge slot this lane evaluates
    int h  = t >> 3;  // fma-phase: head of this lane's channel t
    float adh = ad[n * NH + ih];
    int beg = __builtin_amdgcn_readfirstlane(rowptr[n]);
    int end = __builtin_amdgcn_readfirstlane(rowptr[n + 1]);
    float acc = 0.f, den = 0.f;
    for (int j0 = beg; j0 < end; j0 += 8) {
        int m = end - j0; if (m > 8) m = 8;
        // e-phase: 64 lanes compute w(edge ie, head ih), each exp exactly once
        float w_t = 0.f;
        if (ie < m) {
            int s_t = esrc[j0 + ie];
            float e = as[s_t * NH + ih] + adh;
            e = (e > 0.f) ? e : NEG * e;
            w_t = __expf(e);
        }
        // fma-phase: per edge k, broadcast w(k, h) from lane (k<<3)|h; s from S-load
        int k = 0;
        for (; k + 3 < m; k += 4) {
            int s0 = __builtin_amdgcn_readfirstlane(esrc[j0 + k]);
            int s1 = __builtin_amdgcn_readfirstlane(esrc[j0 + k + 1]);
            int s2 = __builtin_amdgcn_readfirstlane(esrc[j0 + k + 2]);
            int s3 = __builtin_amdgcn_readfirstlane(esrc[j0 + k + 3]);
            float v0 = __bfloat162float(h1b[(size_t)s0 * HH + t]);
            float v1 = __bfloat162float(h1b[(size_t)s1 * HH + t]);
            float v2 = __bfloat162float(h1b[(size_t)s2 * HH + t]);
            float v3 = __bfloat162float(h1b[(size_t)s3 * HH + t]);
            float w0 = __shfl(w_t, ((k    ) << 3) | h);
            float w1 = __shfl(w_t, ((k + 1) << 3) | h);
            float w2 = __shfl(w_t, ((k + 2) << 3) | h);
            float w3 = __shfl(w_t, ((k + 3) << 3) | h);
            den += (w0 + w1) + (w2 + w3);
            acc = fmaf(w0, v0, acc);
            acc = fmaf(w1, v1, acc);
            acc = fmaf(w2, v2, acc);
            acc = fmaf(w3, v3, acc);
        }
        for (; k < m; ++k) {
            int s0 = __builtin_amdgcn_readfirstlane(esrc[j0 + k]);
            float w0 = __shfl(w_t, (k << 3) | h);
            den += w0;
            acc = fmaf(w0, __bfloat162float(h1b[(size_t)s0 * HH + t]), acc);
        }
    }
    float o = acc / (den + 1e-16f) + b1[t];
    hmid[(size_t)n * HH + t] = (o > 0.f) ? o : expm1f(o);  // ELU
}

// ---------------- Layer 2 ----------------

// h2b[N,40](bf16) = hmid[N,64] @ W2[64,40]; also a_src2/a_dst2 [N] (f32, from f32 acc)
__global__ __launch_bounds__(256) void k_gemm2(const float* __restrict__ hmid, const float* __restrict__ W2,
                                               const float* __restrict__ as2w, const float* __restrict__ ad2w,
                                               bf16* __restrict__ h2b, float* __restrict__ as2,
                                               float* __restrict__ ad2) {
    __shared__ float w2s[64 * C2];
    __shared__ float hrow[4][64];
    int t = threadIdx.x;
    for (int i = t; i < 64 * C2; i += 256) w2s[i] = W2[i];
    __syncthreads();
    int wv = t >> 6, ln = t & 63;
    int n = blockIdx.x * 4 + wv;
    hrow[wv][ln] = hmid[(size_t)n * HH + ln];
    __syncthreads();
    float acc = 0.f;
    if (ln < C2) {
#pragma unroll 8
        for (int k = 0; k < 64; ++k) acc = fmaf(hrow[wv][k], w2s[k * C2 + ln], acc);
    }
    float sv = 0.f, dv = 0.f;
    if (ln < C2) {
        h2b[(size_t)n * C2 + ln] = __float2bfloat16(acc);
        sv = acc * as2w[ln];
        dv = acc * ad2w[ln];
    }
#pragma unroll
    for (int off = 32; off > 0; off >>= 1) {
        sv += __shfl_xor(sv, off);
        dv += __shfl_xor(dv, off);
    }
    if (ln == 0) { as2[n] = sv; ad2[n] = dv; }
}

// one wave per node; batch of 64 edges in e-phase (one per lane), readlane in fma-phase;
// lane t<40 owns class t; fused log_softmax
__global__ __launch_bounds__(256) void k_aggr2(const bf16* __restrict__ h2b, const float* __restrict__ as2,
                                               const float* __restrict__ ad2, const int* __restrict__ rowptr,
                                               const int* __restrict__ esrc, const float* __restrict__ b2,
                                               float* __restrict__ out) {
    int wv = __builtin_amdgcn_readfirstlane(threadIdx.x >> 6);
    int t = threadIdx.x & 63;
    int n = blockIdx.x * 4 + wv;
    float adn = ad2[n];
    int beg = __builtin_amdgcn_readfirstlane(rowptr[n]);
    int end = __builtin_amdgcn_readfirstlane(rowptr[n + 1]);
    bool act = (t < C2);
    int tc = act ? t : 0;  // clamp: lanes 40..63 duplicate class 0 (discarded)
    float acc = 0.f, den_p = 0.f;
    for (int j0 = beg; j0 < end; j0 += 64) {
        int m = end - j0; if (m > 64) m = 64;
        // e-phase: one edge per lane
        float w_t = 0.f;
        if (t < m) {
            int s_t = esrc[j0 + t];
            float e = as2[s_t] + adn;
            e = (e > 0.f) ? e : NEG * e;
            w_t = __expf(e);
        }
        den_p += w_t;
        // fma-phase: uniform readlane broadcast of w, S-load of s
        int k = 0;
        for (; k + 3 < m; k += 4) {
            int s0 = __builtin_amdgcn_readfirstlane(esrc[j0 + k]);
            int s1 = __builtin_amdgcn_readfirstlane(esrc[j0 + k + 1]);
            int s2 = __builtin_amdgcn_readfirstlane(esrc[j0 + k + 2]);
            int s3 = __builtin_amdgcn_readfirstlane(esrc[j0 + k + 3]);
            float v0 = __bfloat162float(h2b[(size_t)s0 * C2 + tc]);
            float v1 = __bfloat162float(h2b[(size_t)s1 * C2 + tc]);
            float v2 = __bfloat162float(h2b[(size_t)s2 * C2 + tc]);
            float v3 = __bfloat162float(h2b[(size_t)s3 * C2 + tc]);
            float w0 = __shfl(w_t, k);
            float w1 = __shfl(w_t, k + 1);
            float w2 = __shfl(w_t, k + 2);
            float w3 = __shfl(w_t, k + 3);
            acc = fmaf(w0, v0, acc);
            acc = fmaf(w1, v1, acc);
            acc = fmaf(w2, v2, acc);
            acc = fmaf(w3, v3, acc);
        }
        for (; k < m; ++k) {
            int s0 = __builtin_amdgcn_readfirstlane(esrc[j0 + k]);
            float w0 = __shfl(w_t, k);
            acc = fmaf(w0, __bfloat162float(h2b[(size_t)s0 * C2 + tc]), acc);
        }
    }
    // reduce den across the wave (lanes beyond degree contributed 0)
    float den = den_p;
#pragma unroll
    for (int off = 32; off > 0; off >>= 1) den += __shfl_xor(den, off);
    float o = act ? (acc / (den + 1e-16f) + b2[t]) : -1e30f;
    float mx = o;
#pragma unroll
    for (int off = 32; off > 0; off >>= 1) mx = fmaxf(mx, __shfl_xor(mx, off));
    float ex = act ? __expf(o - mx) : 0.f;
    float sm = ex;
#pragma unroll
    for (int off = 32; off > 0; off >>= 1) sm += __shfl_xor(sm, off);
    if (act) out[(size_t)n * C2 + t] = o - mx - logf(sm);
}

// ---------------- launch ----------------

extern "C" void kernel_launch(void* const* d_in, const int* in_sizes, int n_in,
                              void* d_out, int out_size, void* d_ws, size_t ws_size,
                              hipStream_t stream) {
    const float* x    = (const float*)d_in[0];
    const int*   ei   = (const int*)d_in[1];
    const float* W1   = (const float*)d_in[2];
    const float* as1w = (const float*)d_in[3];
    const float* ad1w = (const float*)d_in[4];
    const float* b1   = (const float*)d_in[5];
    const float* W2   = (const float*)d_in[6];
    const float* as2w = (const float*)d_in[7];
    const float* ad2w = (const float*)d_in[8];
    const float* b2   = (const float*)d_in[9];
    float* out = (float*)d_out;

    // workspace layout; CSR temporaries alias later-written buffers (all CSR kernels
    // complete before the aliased partner is first written, same stream)
    char* ws = (char*)d_ws;
    bf16*  h1b     = (bf16*) (ws + 0);            // 12,800,000 B
    float* as1     = (float*)(ws + 12800000);     //  3,200,000 B
    float* ad1     = (float*)(ws + 16000000);     //  3,200,000 B
    float* hmid    = (float*)(ws + 19200000);     // 25,600,000 B
    unsigned int* pb = (unsigned int*)(ws + 19200000); // 13,200,000 B (alias hmid; dead after k_bucket)
    bf16*  h2b     = (bf16*) (ws + 44800000);     //  8,000,000 B
    int*   bhist   = (int*)  (ws + 44800000);     //    630,292 B (alias h2b; dead after k_scat1)
    float* as2     = (float*)(ws + 52800000);     //    400,000 B
    int*   bktBase = (int*)  (ws + 52800000);     //      1,568 B (alias as2; dead after k_bucket)
    float* ad2     = (float*)(ws + 53200000);     //    400,000 B
    int*   bktTot  = (int*)  (ws + 53200000);     //      1,564 B (alias ad2; dead after k_base)
    int*   rowp    = (int*)  (ws + 53600000);     //    400,004 B
    int*   esrc    = (int*)  (ws + 54000256);     // 13,200,000 B -> total ~67.2 MB

    k_bhist <<<NBLK, 256, 0, stream>>>(ei, bhist);
    k_bscan <<<NBKT, 512, 0, stream>>>(bhist, bktTot);
    k_base  <<<1,    512, 0, stream>>>(bktTot, bktBase, rowp);
    k_scat1 <<<NBLK, 256, 0, stream>>>(ei, bhist, bktBase, pb);
    k_bucket<<<NBKT, 256, 0, stream>>>(pb, bktBase, rowp, esrc);
    k_gemm1 <<<NNODES / 32, 256, 0, stream>>>(x, W1, as1w, ad1w, h1b, as1, ad1);
    k_aggr1 <<<NNODES / 4, 256, 0, stream>>>(h1b, as1, ad1, rowp, esrc, b1, hmid);
    k_gemm2 <<<NNODES / 4, 256, 0, stream>>>(hmid, W2, as2w, ad2w, h2b, as2, ad2);
    k_aggr2 <<<NNODES / 4, 256, 0, stream>>>(h2b, as2, ad2, rowp, esrc, b2, out);
}